// Round 5
// baseline (575.320 us; speedup 1.0000x reference)
//
#include <hip/hip_runtime.h>

#define NB   4096
#define NIN  1024
#define NH   2048
#define NOUT 1024
#define NH4  8192   // 4*NH

typedef short short8 __attribute__((ext_vector_type(8)));
typedef float f32x4 __attribute__((ext_vector_type(4)));
typedef float f32x16 __attribute__((ext_vector_type(16)));
typedef unsigned short ushort8v __attribute__((ext_vector_type(8)));

__device__ __forceinline__ float bf2f(unsigned short u) {
  union { unsigned int i; float f; } c; c.i = ((unsigned int)u) << 16; return c.f;
}
__device__ __forceinline__ unsigned short f2bf(float f) {
  union { float f; unsigned int i; } c; c.f = f;
  unsigned int u = c.i;
  u += 0x7FFFu + ((u >> 16) & 1u);   // RNE; inputs are finite
  return (unsigned short)(u >> 16);
}
__device__ __forceinline__ float sigf(float x) { return 1.0f / (1.0f + __expf(-x)); }
__device__ __forceinline__ float tanh_f(float x) { return 1.0f - 2.0f / (__expf(2.0f * x) + 1.0f); }

// ---------------- workspace layout (ushort elems), compile-time ----------------
// [cvt region: inp,h0,Wx*4,Wh*4,Wd][Zx][Zh][HXb]; decoder fp32 partials reuse
// [0, OFF_WD) (Xb/H0b/Wx/Wh are dead once gemm_dual completes; Wd must survive).
#define CNT_INP  ((size_t)NB * NIN)
#define CNT_H0   ((size_t)NB * NH)
#define CNT_WXG  ((size_t)NH * NIN)
#define CNT_WHG  ((size_t)NH * NH)
#define CNT_WD   ((size_t)NOUT * NH)
#define OFF_XB   ((size_t)0)
#define OFF_H0B  (OFF_XB + CNT_INP)
#define OFF_WX   (OFF_H0B + CNT_H0)
#define OFF_WH   (OFF_WX + 4 * CNT_WXG)
#define OFF_WD   (OFF_WH + 4 * CNT_WHG)
#define OFF_ZX   (OFF_WD + CNT_WD)
#define OFF_ZH   (OFF_ZX + (size_t)NB * NH4)
#define OFF_HXB  (OFF_ZH + (size_t)NB * NH4)
#define CVT_TOTAL (OFF_WD + CNT_WD)
// partials: 4 slices of NB*NOUT fp32 = 67.1 MB < 75.5 MB available at offset 0

// ---------------- single fused fp32->bf16 convert over all 11 segments ----------------
struct CvtArgs { const float* src[11]; };

__global__ __launch_bounds__(256) void cvt_all(CvtArgs a, unsigned short* __restrict__ dstBase) {
  const size_t i = ((size_t)blockIdx.x * 256 + threadIdx.x) * 8;
  if (i >= CVT_TOTAL) return;
  const size_t cnt[11] = {CNT_INP, CNT_H0, CNT_WXG, CNT_WXG, CNT_WXG, CNT_WXG,
                          CNT_WHG, CNT_WHG, CNT_WHG, CNT_WHG, CNT_WD};
  const size_t dst[11] = {OFF_XB, OFF_H0B,
                          OFF_WX, OFF_WX + CNT_WXG, OFF_WX + 2 * CNT_WXG, OFF_WX + 3 * CNT_WXG,
                          OFF_WH, OFF_WH + CNT_WHG, OFF_WH + 2 * CNT_WHG, OFF_WH + 3 * CNT_WHG,
                          OFF_WD};
  size_t base = 0;
#pragma unroll
  for (int s = 0; s < 11; s++) {
    if (i < base + cnt[s]) {
      const size_t off = i - base;
      const float* sp = a.src[s] + off;
      float4 v0 = *(const float4*)(sp);
      float4 v1 = *(const float4*)(sp + 4);
      ushort8v o;
      o[0] = f2bf(v0.x); o[1] = f2bf(v0.y); o[2] = f2bf(v0.z); o[3] = f2bf(v0.w);
      o[4] = f2bf(v1.x); o[5] = f2bf(v1.y); o[6] = f2bf(v1.z); o[7] = f2bf(v1.w);
      *(ushort8v*)(dstBase + dst[s] + off) = o;
      return;
    }
    base += cnt[s];
  }
}

// ---------------- async global->LDS, 16B/lane ----------------
__device__ __forceinline__ void gload16(const void* g, void* l) {
  __builtin_amdgcn_global_load_lds((const __attribute__((address_space(1))) void*)g,
                                   (__attribute__((address_space(3))) void*)l, 16, 0, 0);
}

// ---------------- NT GEMM core, 32x32x16 MFMA, BK=64 ----------------
// C[m][n] = sum_{k0..k0+KL} A[m][k]*B[n][k] (+ bias[n] if BIAS).  ld = row stride
// (= K for full-K, may exceed KL for split-K slices; caller pre-offsets A/B).
// LDS swizzle swz(r) = (r&7)^((r>>3)&3): verified 0 conflicts (R4 counters).
// A/B frag: m(n)=lane&31, k=(lane>>5)*8+i. C/D: col=lane&31,
// row=(reg&3)+8*(reg>>2)+4*(lane>>5)  [measured m74/m101].
template<int MT, bool BOUT, bool BIAS>
__device__ __forceinline__ void gemm_core32(const unsigned short* __restrict__ A,
                                            const unsigned short* __restrict__ Bm,
                                            const float* b0p, const float* b1p,
                                            const float* b2p, const float* b3p,
                                            float* __restrict__ Cf, unsigned short* __restrict__ Cb,
                                            int N, int KL, int ld) {
  constexpr int TM = MT * 64;
  __shared__ __align__(16) unsigned short As[TM * 64];
  __shared__ __align__(16) unsigned short Bs[128 * 64];
  const int t = threadIdx.x;
  const int w = t >> 6;
  const int lane = t & 63;
  const int r31 = lane & 31;
  const int hi = lane >> 5;
  const int rloc = lane >> 3;      // staging: row within 8-row issue group
  const int slot = lane & 7;       // staging: LDS slot within row
  const int m0 = blockIdx.y * TM;
  const int n0 = blockIdx.x * 128;
  const int wm = (w >> 1) * (MT * 32);
  const int wn = (w & 1) * 64;

  f32x16 acc[MT][2];
#pragma unroll
  for (int i = 0; i < MT; i++)
#pragma unroll
    for (int j = 0; j < 2; j++)
#pragma unroll
      for (int r = 0; r < 16; r++) acc[i][j][r] = 0.f;

  // staging pointers: A has 2*MT issues/wave, B has 4 issues/wave; issue idx = w + 4*q
  const unsigned short* AgP[2 * MT];
  unsigned short* AsP[2 * MT];
#pragma unroll
  for (int q = 0; q < 2 * MT; q++) {
    const int iss = w + 4 * q;
    const int bblk = slot ^ rloc ^ (iss & 3);   // global 16B k-block for this lane
    AgP[q] = A + (size_t)(m0 + iss * 8 + rloc) * ld + bblk * 8;
    AsP[q] = As + iss * 512;
  }
  const unsigned short* BgP[4];
  unsigned short* BsP[4];
#pragma unroll
  for (int q = 0; q < 4; q++) {
    const int iss = w + 4 * q;
    const int bblk = slot ^ rloc ^ (iss & 3);
    BgP[q] = Bm + (size_t)(n0 + iss * 8 + rloc) * ld + bblk * 8;
    BsP[q] = Bs + iss * 512;
  }

  const int swz = (r31 & 7) ^ ((r31 >> 3) & 3);

  for (int k0 = 0; k0 < KL; k0 += 64) {
#pragma unroll
    for (int q = 0; q < 2 * MT; q++) gload16(AgP[q] + k0, AsP[q]);
#pragma unroll
    for (int q = 0; q < 4; q++) gload16(BgP[q] + k0, BsP[q]);
    __syncthreads();

#pragma unroll
    for (int ks = 0; ks < 4; ks++) {
      const int phys = ((ks * 2 + hi) ^ swz) * 8;
      short8 af[MT], bf[2];
#pragma unroll
      for (int mt = 0; mt < MT; mt++) af[mt] = *(const short8*)&As[(wm + mt * 32 + r31) * 64 + phys];
#pragma unroll
      for (int jt = 0; jt < 2; jt++) bf[jt] = *(const short8*)&Bs[(wn + jt * 32 + r31) * 64 + phys];
#pragma unroll
      for (int mt = 0; mt < MT; mt++)
#pragma unroll
        for (int jt = 0; jt < 2; jt++)
          acc[mt][jt] = __builtin_amdgcn_mfma_f32_32x32x16_bf16(af[mt], bf[jt], acc[mt][jt], 0, 0, 0);
    }
    __syncthreads();
  }

  // epilogue
#pragma unroll
  for (int mt = 0; mt < MT; mt++) {
#pragma unroll
    for (int jt = 0; jt < 2; jt++) {
      const int col = n0 + wn + jt * 32 + r31;
      float bv = 0.0f;
      if (BIAS) {
        const float* bp = (col < 2048) ? b0p : ((col < 4096) ? b1p : ((col < 6144) ? b2p : b3p));
        bv = bp[col & 2047];
      }
      const int rowb = m0 + wm + mt * 32 + hi * 4;
#pragma unroll
      for (int reg = 0; reg < 16; reg++) {
        const int row = rowb + (reg & 3) + 8 * (reg >> 2);
        const float v = acc[mt][jt][reg] + bv;
        const size_t idx = (size_t)row * N + col;
        if (BOUT) Cb[idx] = f2bf(v);
        else      Cf[idx] = v;
      }
    }
  }
}

// Zx and Zh fused in one grid (z=0: x-side K=1024, z=1: h-side K=2048).
__global__ __launch_bounds__(256) void gemm_dual(const unsigned short* __restrict__ Xb,
                                                 const unsigned short* __restrict__ Wx,
                                                 const unsigned short* __restrict__ H0b,
                                                 const unsigned short* __restrict__ Wh,
                                                 const float* bx0, const float* bx1,
                                                 const float* bx2, const float* bx3,
                                                 const float* bh0, const float* bh1,
                                                 const float* bh2, const float* bh3,
                                                 unsigned short* __restrict__ Zx,
                                                 unsigned short* __restrict__ Zh) {
  if (blockIdx.z == 0)
    gemm_core32<2, true, true>(Xb, Wx, bx0, bx1, bx2, bx3, nullptr, Zx, NH4, NIN, NIN);
  else
    gemm_core32<2, true, true>(H0b, Wh, bh0, bh1, bh2, bh3, nullptr, Zh, NH4, NH, NH);
}

// decoder split-K: z = K-slice (4 x 512); 64x128 tiles -> 2048 blocks (8/CU).
// Writes fp32 partials (no bias); reduce kernel sums + bias.
__global__ __launch_bounds__(256) void gemm_dec(const unsigned short* __restrict__ HXb,
                                                const unsigned short* __restrict__ Wd,
                                                float* __restrict__ partials) {
  const int kz = blockIdx.z;
  gemm_core32<1, false, false>(HXb + kz * 512, Wd + kz * 512, nullptr, nullptr, nullptr, nullptr,
                               partials + (size_t)kz * NB * NOUT, nullptr, NOUT, 512, NH);
}

__global__ __launch_bounds__(256) void dec_reduce(const float* __restrict__ partials,
                                                  const float* __restrict__ bdec,
                                                  float* __restrict__ out) {
  const size_t i = ((size_t)blockIdx.x * 256 + threadIdx.x) * 4;
  const size_t total = (size_t)NB * NOUT;
  if (i >= total) return;
  float4 p0 = *(const float4*)(partials + i);
  float4 p1 = *(const float4*)(partials + total + i);
  float4 p2 = *(const float4*)(partials + 2 * total + i);
  float4 p3 = *(const float4*)(partials + 3 * total + i);
  float4 bv = *(const float4*)(bdec + (i & (NOUT - 1)));
  float4 r;
  r.x = p0.x + p1.x + p2.x + p3.x + bv.x;
  r.y = p0.y + p1.y + p2.y + p3.y + bv.y;
  r.z = p0.z + p1.z + p2.z + p3.z + bv.z;
  r.w = p0.w + p1.w + p2.w + p3.w + bv.w;
  *(float4*)(out + i) = r;
}

// ---------------- fused LN(zx)+LN(zh) -> gates -> cx -> LN(cx) -> hx ----------------
__global__ __launch_bounds__(256) void ln_gates(const unsigned short* __restrict__ Zx,
                                                const unsigned short* __restrict__ Zh,
                                                const float* __restrict__ c0,
                                                const float* __restrict__ ax, const float* __restrict__ bx,
                                                const float* __restrict__ ah, const float* __restrict__ bh,
                                                const float* __restrict__ ac, const float* __restrict__ bc,
                                                float* __restrict__ out_top,
                                                unsigned short* __restrict__ hx_bf) {
  const int b = blockIdx.x;
  const int t = threadIdx.x;
  const int n = t * 8;
  const int w = t >> 6;
  const int lane = t & 63;
  const float inv_n = 1.0f / 2048.0f, inv_nm1 = 1.0f / 2047.0f;

  short8 zx[4], zh[4];
  const size_t rowoff = (size_t)b * NH4;
#pragma unroll
  for (int g = 0; g < 4; g++) {
    zx[g] = *(const short8*)(Zx + rowoff + g * NH + n);
    zh[g] = *(const short8*)(Zh + rowoff + g * NH + n);
  }

  float s[16];
#pragma unroll
  for (int g = 0; g < 4; g++) {
    float su = 0, sq = 0, su2 = 0, sq2 = 0;
#pragma unroll
    for (int j = 0; j < 8; j++) {
      float v = bf2f((unsigned short)zx[g][j]); su += v; sq += v * v;
      float u = bf2f((unsigned short)zh[g][j]); su2 += u; sq2 += u * u;
    }
    s[g * 4 + 0] = su; s[g * 4 + 1] = sq; s[g * 4 + 2] = su2; s[g * 4 + 3] = sq2;
  }
#pragma unroll
  for (int i = 0; i < 16; i++) {
    float v = s[i];
#pragma unroll
    for (int o = 32; o > 0; o >>= 1) v += __shfl_xor(v, o, 64);
    s[i] = v;
  }
  __shared__ float red[4][16];
  __shared__ float red2[4][2];
  if (lane == 0) {
#pragma unroll
    for (int i = 0; i < 16; i++) red[w][i] = s[i];
  }
  __syncthreads();
#pragma unroll
  for (int i = 0; i < 16; i++) s[i] = red[0][i] + red[1][i] + red[2][i] + red[3][i];

  float mux[4], ivx[4], muh[4], ivh[4];
#pragma unroll
  for (int g = 0; g < 4; g++) {
    mux[g] = s[g * 4 + 0] * inv_n;
    float vx = fmaxf((s[g * 4 + 1] - s[g * 4 + 0] * mux[g]) * inv_nm1, 0.0f);
    ivx[g] = 1.0f / (sqrtf(vx) + 1e-5f);
    muh[g] = s[g * 4 + 2] * inv_n;
    float vh = fmaxf((s[g * 4 + 3] - s[g * 4 + 2] * muh[g]) * inv_nm1, 0.0f);
    ivh[g] = 1.0f / (sqrtf(vh) + 1e-5f);
  }

  float axl[8], bxl[8], ahl[8], bhl[8], c0l[8];
  *(float4*)&axl[0] = *(const float4*)(ax + n); *(float4*)&axl[4] = *(const float4*)(ax + n + 4);
  *(float4*)&bxl[0] = *(const float4*)(bx + n); *(float4*)&bxl[4] = *(const float4*)(bx + n + 4);
  *(float4*)&ahl[0] = *(const float4*)(ah + n); *(float4*)&ahl[4] = *(const float4*)(ah + n + 4);
  *(float4*)&bhl[0] = *(const float4*)(bh + n); *(float4*)&bhl[4] = *(const float4*)(bh + n + 4);
  const float* c0p = c0 + (size_t)b * NH + n;
  *(float4*)&c0l[0] = *(const float4*)(c0p); *(float4*)&c0l[4] = *(const float4*)(c0p + 4);

  float cx[8], og[8];
  float cs = 0, css = 0;
#pragma unroll
  for (int j = 0; j < 8; j++) {
    float pre[4];
#pragma unroll
    for (int g = 0; g < 4; g++) {
      float vx = bf2f((unsigned short)zx[g][j]);
      float vh = bf2f((unsigned short)zh[g][j]);
      pre[g] = ((vx - mux[g]) * ivx[g]) * axl[j] + bxl[j]
             + ((vh - muh[g]) * ivh[g]) * ahl[j] + bhl[j];
    }
    float fg = sigf(pre[0]);
    float ig = sigf(pre[1]);
    float ct = tanh_f(pre[2]);
    og[j] = sigf(pre[3]);
    float c = fg * c0l[j] + ig * ct;
    cx[j] = c; cs += c; css += c * c;
  }
#pragma unroll
  for (int o = 32; o > 0; o >>= 1) { cs += __shfl_xor(cs, o, 64); css += __shfl_xor(css, o, 64); }
  if (lane == 0) { red2[w][0] = cs; red2[w][1] = css; }
  __syncthreads();
  cs = red2[0][0] + red2[1][0] + red2[2][0] + red2[3][0];
  css = red2[0][1] + red2[1][1] + red2[2][1] + red2[3][1];
  const float muc = cs * inv_n;
  const float varc = fmaxf((css - cs * muc) * inv_nm1, 0.0f);
  const float ivc = 1.0f / (sqrtf(varc) + 1e-5f);

  float acl[8], bcl[8];
  *(float4*)&acl[0] = *(const float4*)(ac + n); *(float4*)&acl[4] = *(const float4*)(ac + n + 4);
  *(float4*)&bcl[0] = *(const float4*)(bc + n); *(float4*)&bcl[4] = *(const float4*)(bc + n + 4);

  float hx[8];
#pragma unroll
  for (int j = 0; j < 8; j++)
    hx[j] = og[j] * tanh_f((cx[j] - muc) * ivc * acl[j] + bcl[j]);

  // outputs: d_out = [out(B,OUT) | hx(B,H) | cx(B,H)]
  float* hx_out = out_top + (size_t)NB * NOUT + (size_t)b * NH + n;
  float* cx_out = out_top + (size_t)NB * NOUT + (size_t)NB * NH + (size_t)b * NH + n;
  float4 v;
  v.x = hx[0]; v.y = hx[1]; v.z = hx[2]; v.w = hx[3]; *(float4*)(hx_out) = v;
  v.x = hx[4]; v.y = hx[5]; v.z = hx[6]; v.w = hx[7]; *(float4*)(hx_out + 4) = v;
  v.x = cx[0]; v.y = cx[1]; v.z = cx[2]; v.w = cx[3]; *(float4*)(cx_out) = v;
  v.x = cx[4]; v.y = cx[5]; v.z = cx[6]; v.w = cx[7]; *(float4*)(cx_out + 4) = v;
  ushort8v hb;
#pragma unroll
  for (int j = 0; j < 8; j++) hb[j] = f2bf(hx[j]);
  *(ushort8v*)(hx_bf + (size_t)b * NH + n) = hb;
}

extern "C" void kernel_launch(void* const* d_in, const int* in_sizes, int n_in,
                              void* d_out, int out_size, void* d_ws, size_t ws_size,
                              hipStream_t stream) {
  const float* inp = (const float*)d_in[0];
  const float* h0  = (const float*)d_in[1];
  const float* c0  = (const float*)d_in[2];
  const float* bhg[4] = {(const float*)d_in[4], (const float*)d_in[6], (const float*)d_in[8], (const float*)d_in[10]};
  const float* bxg[4] = {(const float*)d_in[12], (const float*)d_in[14], (const float*)d_in[16], (const float*)d_in[18]};
  const float* bdec = (const float*)d_in[20];
  const float* ax = (const float*)d_in[21];
  const float* bx = (const float*)d_in[22];
  const float* ah = (const float*)d_in[23];
  const float* bh = (const float*)d_in[24];
  const float* ac = (const float*)d_in[25];
  const float* bc = (const float*)d_in[26];

  unsigned short* wsb = (unsigned short*)d_ws;
  unsigned short* Xb   = wsb + OFF_XB;
  unsigned short* H0b  = wsb + OFF_H0B;
  unsigned short* Wx4b = wsb + OFF_WX;
  unsigned short* Wh4b = wsb + OFF_WH;
  unsigned short* Wdb  = wsb + OFF_WD;
  unsigned short* Zx   = wsb + OFF_ZX;
  unsigned short* Zh   = wsb + OFF_ZH;
  unsigned short* HXb  = wsb + OFF_HXB;
  float* Pp = (float*)d_ws;   // decoder partials reuse [0, OFF_WD) — dead by dec time

  CvtArgs ca;
  ca.src[0] = inp; ca.src[1] = h0;
  ca.src[2] = (const float*)d_in[11]; ca.src[3] = (const float*)d_in[13];
  ca.src[4] = (const float*)d_in[15]; ca.src[5] = (const float*)d_in[17];
  ca.src[6] = (const float*)d_in[3];  ca.src[7] = (const float*)d_in[5];
  ca.src[8] = (const float*)d_in[7];  ca.src[9] = (const float*)d_in[9];
  ca.src[10] = (const float*)d_in[19];
  {
    const size_t nthr = CVT_TOTAL / 8;
    cvt_all<<<dim3((unsigned)((nthr + 255) / 256)), dim3(256), 0, stream>>>(ca, wsb);
  }

  gemm_dual<<<dim3(NH4 / 128, NB / 128, 2), 256, 0, stream>>>(
      Xb, Wx4b, H0b, Wh4b,
      bxg[0], bxg[1], bxg[2], bxg[3],
      bhg[0], bhg[1], bhg[2], bhg[3],
      Zx, Zh);

  ln_gates<<<dim3(NB), 256, 0, stream>>>(Zx, Zh, c0, ax, bx, ah, bh, ac, bc, (float*)d_out, HXb);

  // decoder: 4-way split-K partials (2048 blocks, 8/CU) then reduce+bias
  gemm_dec<<<dim3(NOUT / 128, NB / 64, 4), 256, 0, stream>>>(HXb, Wdb, Pp);
  dec_reduce<<<dim3((unsigned)(((size_t)NB * NOUT / 4 + 255) / 256)), 256, 0, stream>>>(
      Pp, bdec, (float*)d_out);
}